// Round 1
// baseline (205.125 us; speedup 1.0000x reference)
//
#include <hip/hip_runtime.h>

#define UNITS 20

typedef __attribute__((ext_vector_type(8))) short short8;
typedef __attribute__((ext_vector_type(4))) float floatx4;
typedef __attribute__((ext_vector_type(4))) unsigned int u32x4;
typedef unsigned int u32;
typedef unsigned short u16;

__device__ __forceinline__ float rcpf_fast(float x) { return __builtin_amdgcn_rcpf(x); }
__device__ __forceinline__ float sigmoidf_fast(float x) { return rcpf_fast(1.0f + __expf(-x)); }
__device__ __forceinline__ float tanhf_fast(float x) { return 1.0f - 2.0f * rcpf_fast(1.0f + __expf(2.0f * x)); }

__device__ __forceinline__ u32 f2bf(float f) {
  u32 u = __builtin_bit_cast(u32, f);
  u += 0x7fffu + ((u >> 16) & 1u);   // RNE
  return u >> 16;
}
// packed f32->bf16 (RNE): lo -> D[15:0], hi -> D[31:16]
__device__ __forceinline__ u32 cvtpk(float lo, float hi) {
  u32 r;
  asm("v_cvt_pk_bf16_f32 %0, %1, %2" : "=v"(r) : "v"(lo), "v"(hi));
  return r;
}

// ---------------------------------------------------------------------------
// Prep: pack A-operand fragments for the TRANSPOSED gemms.
//  gates^T = Wcat . Z^T (Wcat = [W_ih | W_hh], 80 x 40, K padded to 64):
//    unchanged permuted layout -> acc[t][reg] (lane q,m) = gate[reg*20+q*5+t].
//  lateral^T = W_lat . Hl^T with K-axis PERMUTATION sigma(q*8+j) = q*5+j
//    (j<5; j>=5 is zero pad). This makes the main kernel's lateral B-operand
//    lane-local: lane (m,q) supplies exactly its own 5 h_lstm values.
//  bias4[u] = (bi, bf, bg, bo) for unit u.
// ---------------------------------------------------------------------------
__global__ void prep_kernel(const float* __restrict__ W_ih, const float* __restrict__ W_hh,
                            const float* __restrict__ b_ih, const float* __restrict__ b_hh,
                            const float* __restrict__ W_lat,
                            u16* __restrict__ fragsG, u16* __restrict__ fragsL,
                            float4* __restrict__ bias4) {
  int tid = threadIdx.x;
  for (int e = tid; e < 768; e += 256) {   // 10 gate frags + 2 lateral frags
    int fi = e >> 6, lane = e & 63;
    int r = lane & 15, q = lane >> 4;
    short8 v8;
    if (fi < 10) {
      int t = fi >> 1, cc = fi & 1;
      int gr = (r & 3) * 20 + (r >> 2) * 5 + t;   // permuted gate row
#pragma unroll
      for (int j = 0; j < 8; ++j) {
        int k = cc * 32 + q * 8 + j;
        float v = 0.0f;
        if (k < 20) v = W_ih[gr * UNITS + k];
        else if (k < 40) v = W_hh[gr * UNITS + (k - 20)];
        v8[j] = (short)f2bf(v);
      }
      *(short8*)(fragsG + (size_t)e * 8) = v8;
    } else {
      int t = fi - 10;
      int vr = t * 16 + r;
#pragma unroll
      for (int j = 0; j < 8; ++j) {
        // sigma-permuted K: k = q*8+j holds W_lat column q*5+j (j<5), else 0
        float v = (vr < 20 && j < 5) ? W_lat[vr * UNITS + q * 5 + j] : 0.0f;
        v8[j] = (short)f2bf(v);
      }
      *(short8*)(fragsL + (size_t)(t * 64 + lane) * 8) = v8;
    }
  }
  if (tid < 20)
    bias4[tid] = make_float4(b_ih[tid] + b_hh[tid],
                             b_ih[20 + tid] + b_hh[20 + tid],
                             b_ih[40 + tid] + b_hh[40 + tid],
                             b_ih[60 + tid] + b_hh[60 + tid]);
}

// ---------------------------------------------------------------------------
// Main: 256 threads = 4 waves. Each wave independently processes 16 batch
// rows per pass (rows are the MFMA column dim); block grid-strides over
// 64-row chunks. NO batch data in LDS, NO in-loop barriers:
//   - B-frag (x|h) built per-lane from 2 global float4 loads + cvt_pk
//   - c loaded per-lane (5 dwords at row*80 + q*20)
//   - lateral B-operand is lane-local thanks to the sigma-permuted W_lat frag
// LDS holds only the 10 gate A-frags (10240 B), staged once per block.
// ---------------------------------------------------------------------------
__global__ __launch_bounds__(256) void stn_main(
    const float* __restrict__ x, const float* __restrict__ h, const float* __restrict__ c,
    const u16* __restrict__ fragsG, const u16* __restrict__ fragsL,
    const float4* __restrict__ bias4, float* __restrict__ out, int B) {
  __shared__ float4 ldsGf[640];            // 10 frags * 64 lanes * 16B = 10240 B

  // stage gate A-frags once
  {
    const float4* src = (const float4*)fragsG;
    for (int i = threadIdx.x; i < 640; i += 256) ldsGf[i] = src[i];
  }

  const int tid  = threadIdx.x;
  const int lane = tid & 63;
  const int wv   = tid >> 6;
  const int m = lane & 15, q = lane >> 4;

  // loop-invariant per-lane state: bias C-frags + lateral A-frags (registers)
  floatx4 biasr[5];
#pragma unroll
  for (int t = 0; t < 5; ++t) {
    float4 b4 = bias4[q * 5 + t];
    biasr[t] = (floatx4){b4.x, b4.y, b4.z, b4.w};
  }
  short8 afL0 = *(const short8*)(fragsL + (size_t)(0 * 64 + lane) * 8);
  short8 afL1 = *(const short8*)(fragsL + (size_t)(1 * 64 + lane) * 8);

  __syncthreads();   // frag staging done — the ONLY barrier in the kernel

  const short8* aG = (const short8*)ldsGf;
  const float4* x4 = (const float4*)x;
  const float4* h4 = (const float4*)h;
  float* outh = out;
  float* outc = out + (size_t)B * UNITS;

  const long stride = 64L * (long)gridDim.x;
  for (long base = (long)blockIdx.x * 64; base < B; base += stride) {
    long row = base + wv * 16 + m;
    bool valid = row < (long)B;
    long rl  = valid ? row : (long)B - 1;   // clamp loads, predicate stores
    long r5  = rl * 5;
    long r20 = rl * 20;

    // ---- per-lane global loads (issue everything up front) ----
    // B-frag cc=0 sources: k = q*8..q*8+8 of z = [x(0..20)|h(20..40)]
    float4 v0 = (q == 3) ? h4[r5 + 1] : x4[r5 + 2 * q];
    float4 v1 = (q == 0) ? x4[r5 + 1]
              : (q == 1) ? x4[r5 + 3]
              : (q == 2) ? h4[r5 + 0] : h4[r5 + 2];
    // c values for this lane's units u = q*5 + t
    const float* cp = c + r20 + q * 5;
    float cv0 = cp[0], cv1 = cp[1], cv2 = cp[2], cv3 = cp[3], cv4 = cp[4];
    // B-frag cc=1: only k=32..40 (= h[12..20)) is nonzero, held by q==0 lanes
    short8 bfr1 = {0, 0, 0, 0, 0, 0, 0, 0};
    if (q == 0) {
      float4 v2 = h4[r5 + 3];
      float4 v3 = h4[r5 + 4];
      u32x4 p1 = {cvtpk(v2.x, v2.y), cvtpk(v2.z, v2.w),
                  cvtpk(v3.x, v3.y), cvtpk(v3.z, v3.w)};
      bfr1 = __builtin_bit_cast(short8, p1);
    }
    u32x4 p0 = {cvtpk(v0.x, v0.y), cvtpk(v0.z, v0.w),
                cvtpk(v1.x, v1.y), cvtpk(v1.z, v1.w)};
    short8 bfr0 = __builtin_bit_cast(short8, p0);

    // ---- gate GEMM: acc[t][reg] = gate[reg*20 + q*5 + t] of batch row m ----
    floatx4 acc[5];
#pragma unroll
    for (int t = 0; t < 5; ++t) {
      acc[t] = __builtin_amdgcn_mfma_f32_16x16x32_bf16(aG[(t * 2 + 0) * 64 + lane], bfr0, biasr[t], 0, 0, 0);
      acc[t] = __builtin_amdgcn_mfma_f32_16x16x32_bf16(aG[(t * 2 + 1) * 64 + lane], bfr1, acc[t], 0, 0, 0);
    }

    // ---- LSTM pointwise, all in-lane: acc[t] = {i,f,g,o} of unit q*5+t ----
    float cvv[5] = {cv0, cv1, cv2, cv3, cv4};
    float cn[5], hl[5];
#pragma unroll
    for (int t = 0; t < 5; ++t) {
      float ig = sigmoidf_fast(acc[t][0]);
      float fg = sigmoidf_fast(acc[t][1]);
      float gg = tanhf_fast(acc[t][2]);
      float og = sigmoidf_fast(acc[t][3]);
      float cnv = fg * cvv[t] + ig * gg;
      cn[t] = cnv;
      hl[t] = og * tanhf_fast(cnv);
    }

    // ---- lateral GEMM: B-operand is lane-local (sigma-permuted K) ----
    u32x4 pl = {cvtpk(hl[0], hl[1]), cvtpk(hl[2], hl[3]), cvtpk(hl[4], 0.0f), 0u};
    short8 bl = __builtin_bit_cast(short8, pl);
    floatx4 z4 = {0.0f, 0.0f, 0.0f, 0.0f};
    floatx4 accL0 = __builtin_amdgcn_mfma_f32_16x16x32_bf16(afL0, bl, z4, 0, 0, 0);
    floatx4 accL1 = __builtin_amdgcn_mfma_f32_16x16x32_bf16(afL1, bl, z4, 0, 0, 0);

    // ---- stores (predicated, per-lane; h coalesces to float4) ----
    if (valid) {
      float* co = outc + r20 + q * 5;
      co[0] = cn[0]; co[1] = cn[1]; co[2] = cn[2]; co[3] = cn[3]; co[4] = cn[4];
      float4 hv;
      hv.x = tanhf_fast(accL0[0]); hv.y = tanhf_fast(accL0[1]);
      hv.z = tanhf_fast(accL0[2]); hv.w = tanhf_fast(accL0[3]);
      *(float4*)(outh + r20 + q * 4) = hv;    // units q*4 .. q*4+4 (v<16)
      if (q == 0) {                            // units 16..20 (tile t=1)
        float4 hw;
        hw.x = tanhf_fast(accL1[0]); hw.y = tanhf_fast(accL1[1]);
        hw.z = tanhf_fast(accL1[2]); hw.w = tanhf_fast(accL1[3]);
        *(float4*)(outh + r20 + 16) = hw;
      }
    }
  }
}

extern "C" void kernel_launch(void* const* d_in, const int* in_sizes, int n_in,
                              void* d_out, int out_size, void* d_ws, size_t ws_size,
                              hipStream_t stream) {
  const float* x     = (const float*)d_in[0];
  const float* h     = (const float*)d_in[1];
  const float* c     = (const float*)d_in[2];
  const float* W_ih  = (const float*)d_in[3];
  const float* W_hh  = (const float*)d_in[4];
  const float* b_ih  = (const float*)d_in[5];
  const float* b_hh  = (const float*)d_in[6];
  const float* W_lat = (const float*)d_in[7];
  float* out = (float*)d_out;

  u16*    fragsG = (u16*)d_ws;                         // 10*64*8*2 = 10240 B
  u16*    fragsL = (u16*)((char*)d_ws + 10240);        //  2*64*8*2 =  2048 B
  float4* bias4  = (float4*)((char*)d_ws + 12288);     //  20*16    =   320 B

  int B = in_sizes[0] / UNITS;
  prep_kernel<<<1, 256, 0, stream>>>(W_ih, W_hh, b_ih, b_hh, W_lat, fragsG, fragsL, bias4);
  long chunks = ((long)B + 63) / 64;
  int grid = (int)(chunks < 2048 ? chunks : 2048);
  stn_main<<<grid, 256, 0, stream>>>(x, h, c, fragsG, fragsL, bias4, out, B);
}

// Round 2
// 203.354 us; speedup vs baseline: 1.0087x; 1.0087x over previous
//
#include <hip/hip_runtime.h>

#define UNITS 20

typedef __attribute__((ext_vector_type(8))) short short8;
typedef __attribute__((ext_vector_type(4))) float floatx4;
typedef __attribute__((ext_vector_type(2))) unsigned int u32x2;
typedef __attribute__((ext_vector_type(4))) unsigned int u32x4;
typedef unsigned int u32;
typedef unsigned short u16;

__device__ __forceinline__ float rcpf_fast(float x) { return __builtin_amdgcn_rcpf(x); }
__device__ __forceinline__ float sigmoidf_fast(float x) { return rcpf_fast(1.0f + __expf(-x)); }
__device__ __forceinline__ float tanhf_fast(float x) { return 1.0f - 2.0f * rcpf_fast(1.0f + __expf(2.0f * x)); }

__device__ __forceinline__ u32 f2bf(float f) {
  u32 u = __builtin_bit_cast(u32, f);
  u += 0x7fffu + ((u >> 16) & 1u);   // RNE
  return u >> 16;
}
// packed f32->bf16 (RNE): lo -> D[15:0], hi -> D[31:16]
__device__ __forceinline__ u32 cvtpk(float lo, float hi) {
  u32 r;
  asm("v_cvt_pk_bf16_f32 %0, %1, %2" : "=v"(r) : "v"(lo), "v"(hi));
  return r;
}

// ---------------------------------------------------------------------------
// Prep (unchanged from round 1): pack A-operand fragments.
//  gates^T = Wcat . Z^T, permuted rows -> acc[t][reg] = gate[reg*20+q*5+t].
//  lateral^T with sigma-permuted K (k=q*8+j holds W_lat col q*5+j, j<5) so
//  the lateral B-operand is lane-local in the main kernel.
// ---------------------------------------------------------------------------
__global__ void prep_kernel(const float* __restrict__ W_ih, const float* __restrict__ W_hh,
                            const float* __restrict__ b_ih, const float* __restrict__ b_hh,
                            const float* __restrict__ W_lat,
                            u16* __restrict__ fragsG, u16* __restrict__ fragsL,
                            float4* __restrict__ bias4) {
  int tid = threadIdx.x;
  for (int e = tid; e < 768; e += 256) {   // 10 gate frags + 2 lateral frags
    int fi = e >> 6, lane = e & 63;
    int r = lane & 15, q = lane >> 4;
    short8 v8;
    if (fi < 10) {
      int t = fi >> 1, cc = fi & 1;
      int gr = (r & 3) * 20 + (r >> 2) * 5 + t;   // permuted gate row
#pragma unroll
      for (int j = 0; j < 8; ++j) {
        int k = cc * 32 + q * 8 + j;
        float v = 0.0f;
        if (k < 20) v = W_ih[gr * UNITS + k];
        else if (k < 40) v = W_hh[gr * UNITS + (k - 20)];
        v8[j] = (short)f2bf(v);
      }
      *(short8*)(fragsG + (size_t)e * 8) = v8;
    } else {
      int t = fi - 10;
      int vr = t * 16 + r;
#pragma unroll
      for (int j = 0; j < 8; ++j) {
        float v = (vr < 20 && j < 5) ? W_lat[vr * UNITS + q * 5 + j] : 0.0f;
        v8[j] = (short)f2bf(v);
      }
      *(short8*)(fragsL + (size_t)(t * 64 + lane) * 8) = v8;
    }
  }
  if (tid < 20)
    bias4[tid] = make_float4(b_ih[tid] + b_hh[tid],
                             b_ih[20 + tid] + b_hh[20 + tid],
                             b_ih[40 + tid] + b_hh[40 + tid],
                             b_ih[60 + tid] + b_hh[60 + tid]);
}

// ---------------------------------------------------------------------------
// Main: 4 independent waves/block, 16 rows/wave/pass, grid-stride chunks.
// ALL global loads wave-coalesced (lane L reads bytes L*16 of the wave's
// contiguous 1280 B row-block per array); redistribution to MFMA fragment
// layout goes through WAVE-PRIVATE LDS (no __syncthreads — same-wave ds
// ordering via lgkmcnt). Next pass's loads are register-prefetched so HBM
// latency hides under MFMA + transcendental work.
// LDS: [0,10240) gate A-frags (shared, staged once);
//      per wave at 10240+wv*2560: Z bf16 [16][40] (1280 B) + C f32 [16][20].
// ---------------------------------------------------------------------------
__global__ __launch_bounds__(256, 4) void stn_main(
    const float* __restrict__ x, const float* __restrict__ h, const float* __restrict__ c,
    const u16* __restrict__ fragsG, const u16* __restrict__ fragsL,
    const float4* __restrict__ bias4, float* __restrict__ out, int B) {
  __shared__ unsigned char smem[20480];

  // stage gate A-frags once (shared by all 4 waves)
  for (int i = threadIdx.x; i < 640; i += 256)
    ((float4*)smem)[i] = ((const float4*)fragsG)[i];

  const int tid  = threadIdx.x;
  const int lane = tid & 63;
  const int wv   = tid >> 6;
  const int m = lane & 15, q = lane >> 4;

  unsigned char* Zb = smem + 10240 + wv * 2560;   // bf16 [16][40]
  float*         Cw = (float*)(Zb + 1280);        // f32  [16][20]

  // lane-constant staging offsets: lane L carries floats 4L..4L+3 of the
  // wave's 320-float block; row m0=L/5 (rows are exactly 5 lanes), k=4*(L%5)
  const int m0 = lane / 5, j0 = lane - m0 * 5;
  const int l1 = 64 + lane;
  const int m1 = l1 / 5, j1 = l1 - m1 * 5;        // tail part (lanes < 16)
  const int zA = m0 * 80 + 8 * j0;                // Z byte offset (x); h at +40
  const int zB = m1 * 80 + 8 * j1;

  // loop-invariant per-lane state
  floatx4 biasr[5];
#pragma unroll
  for (int t = 0; t < 5; ++t) {
    float4 b4 = bias4[q * 5 + t];
    biasr[t] = (floatx4){b4.x, b4.y, b4.z, b4.w};
  }
  short8 afL0 = *(const short8*)(fragsL + (size_t)lane * 8);
  short8 afL1 = *(const short8*)(fragsL + (size_t)(64 + lane) * 8);

  __syncthreads();   // frag staging done — only barrier in the kernel

  const short8* aG = (const short8*)smem;
  float* outh = out;
  float* outc = out + (size_t)B * UNITS;

  const long stride = 64L * (long)gridDim.x;
  long base = (long)blockIdx.x * 64;

  auto rbclamp = [&](long b) {
    long r = b + wv * 16;
    if (r + 16 > (long)B) r = (long)B - 16;   // duplicate-row stores are benign
    if (r < 0) r = 0;
    return r;
  };

  float4 xA, hA, cA;
  float4 xB = {0, 0, 0, 0}, hB = {0, 0, 0, 0}, cB = {0, 0, 0, 0};

  long rb = rbclamp(base);
  {
    const float4* xp = (const float4*)(x + rb * 20);
    const float4* hp = (const float4*)(h + rb * 20);
    const float4* cp = (const float4*)(c + rb * 20);
    xA = xp[lane]; hA = hp[lane]; cA = cp[lane];
    if (lane < 16) { xB = xp[64 + lane]; hB = hp[64 + lane]; cB = cp[64 + lane]; }
  }

  while (true) {
    // ---- stage current pass into wave-private LDS (bf16 pack for x,h) ----
    {
      u32x2 w;
      w[0] = cvtpk(xA.x, xA.y); w[1] = cvtpk(xA.z, xA.w);
      *(u32x2*)(Zb + zA) = w;
      w[0] = cvtpk(hA.x, hA.y); w[1] = cvtpk(hA.z, hA.w);
      *(u32x2*)(Zb + zA + 40) = w;
      *(float4*)((unsigned char*)Cw + lane * 16) = cA;
      if (lane < 16) {
        w[0] = cvtpk(xB.x, xB.y); w[1] = cvtpk(xB.z, xB.w);
        *(u32x2*)(Zb + zB) = w;
        w[0] = cvtpk(hB.x, hB.y); w[1] = cvtpk(hB.z, hB.w);
        *(u32x2*)(Zb + zB + 40) = w;
        *(float4*)((unsigned char*)Cw + 1024 + lane * 16) = cB;
      }
    }

    long nbase = base + stride;
    bool more = nbase < (long)B;

    // ---- read this pass's B-frags + c from wave-private LDS ----
    short8 bfr0 = *(const short8*)(Zb + m * 80 + q * 16);      // z[m][q*8..+8]
    short8 bfr1 = (short8){0, 0, 0, 0, 0, 0, 0, 0};
    if (q == 0) bfr1 = *(const short8*)(Zb + m * 80 + 64);     // z[m][32..40]
    float cvv[5];
#pragma unroll
    for (int t = 0; t < 5; ++t) cvv[t] = Cw[m * 20 + q * 5 + t];

    // ---- prefetch next pass (coalesced; overlaps with compute below) ----
    long rbn = rb;
    if (more) {
      rbn = rbclamp(nbase);
      const float4* xp = (const float4*)(x + rbn * 20);
      const float4* hp = (const float4*)(h + rbn * 20);
      const float4* cp = (const float4*)(c + rbn * 20);
      xA = xp[lane]; hA = hp[lane]; cA = cp[lane];
      if (lane < 16) { xB = xp[64 + lane]; hB = hp[64 + lane]; cB = cp[64 + lane]; }
    }

    // ---- gate GEMM: acc[t][reg] = gate[reg*20 + q*5 + t] of batch row m ----
    floatx4 acc[5];
#pragma unroll
    for (int t = 0; t < 5; ++t) {
      acc[t] = __builtin_amdgcn_mfma_f32_16x16x32_bf16(aG[(t * 2 + 0) * 64 + lane], bfr0, biasr[t], 0, 0, 0);
      acc[t] = __builtin_amdgcn_mfma_f32_16x16x32_bf16(aG[(t * 2 + 1) * 64 + lane], bfr1, acc[t], 0, 0, 0);
    }

    // ---- LSTM pointwise (in-lane): acc[t] = {i,f,g,o} of unit q*5+t ----
    float cn[5], hl[5];
#pragma unroll
    for (int t = 0; t < 5; ++t) {
      float ig = sigmoidf_fast(acc[t][0]);
      float fg = sigmoidf_fast(acc[t][1]);
      float gg = tanhf_fast(acc[t][2]);
      float og = sigmoidf_fast(acc[t][3]);
      float cnv = fg * cvv[t] + ig * gg;
      cn[t] = cnv;
      hl[t] = og * tanhf_fast(cnv);
    }

    // ---- lateral GEMM: B-operand lane-local (sigma-permuted K) ----
    u32x4 pl = {cvtpk(hl[0], hl[1]), cvtpk(hl[2], hl[3]), cvtpk(hl[4], 0.0f), 0u};
    short8 bl = __builtin_bit_cast(short8, pl);
    floatx4 z4 = {0.0f, 0.0f, 0.0f, 0.0f};
    floatx4 accL0 = __builtin_amdgcn_mfma_f32_16x16x32_bf16(afL0, bl, z4, 0, 0, 0);
    floatx4 accL1 = __builtin_amdgcn_mfma_f32_16x16x32_bf16(afL1, bl, z4, 0, 0, 0);

    // ---- stores (per-lane; h is float4) ----
    {
      long r20 = (rb + m) * 20;
      float* co = outc + r20 + q * 5;
      co[0] = cn[0]; co[1] = cn[1]; co[2] = cn[2]; co[3] = cn[3]; co[4] = cn[4];
      float4 hv;
      hv.x = tanhf_fast(accL0[0]); hv.y = tanhf_fast(accL0[1]);
      hv.z = tanhf_fast(accL0[2]); hv.w = tanhf_fast(accL0[3]);
      *(float4*)(outh + r20 + q * 4) = hv;       // units q*4..q*4+4
      if (q == 0) {                               // units 16..20
        float4 hw;
        hw.x = tanhf_fast(accL1[0]); hw.y = tanhf_fast(accL1[1]);
        hw.z = tanhf_fast(accL1[2]); hw.w = tanhf_fast(accL1[3]);
        *(float4*)(outh + r20 + 16) = hw;
      }
    }

    if (!more) break;
    base = nbase; rb = rbn;
  }
}

extern "C" void kernel_launch(void* const* d_in, const int* in_sizes, int n_in,
                              void* d_out, int out_size, void* d_ws, size_t ws_size,
                              hipStream_t stream) {
  const float* x     = (const float*)d_in[0];
  const float* h     = (const float*)d_in[1];
  const float* c     = (const float*)d_in[2];
  const float* W_ih  = (const float*)d_in[3];
  const float* W_hh  = (const float*)d_in[4];
  const float* b_ih  = (const float*)d_in[5];
  const float* b_hh  = (const float*)d_in[6];
  const float* W_lat = (const float*)d_in[7];
  float* out = (float*)d_out;

  u16*    fragsG = (u16*)d_ws;                         // 10*64*8*2 = 10240 B
  u16*    fragsL = (u16*)((char*)d_ws + 10240);        //  2*64*8*2 =  2048 B
  float4* bias4  = (float4*)((char*)d_ws + 12288);     //  20*16    =   320 B

  int B = in_sizes[0] / UNITS;
  prep_kernel<<<1, 256, 0, stream>>>(W_ih, W_hh, b_ih, b_hh, W_lat, fragsG, fragsL, bias4);
  long chunks = ((long)B + 63) / 64;
  int grid = (int)(chunks < 2048 ? chunks : 2048);
  stn_main<<<grid, 256, 0, stream>>>(x, h, c, fragsG, fragsL, bias4, out, B);
}